// Round 5
// baseline (272.666 us; speedup 1.0000x reference)
//
#include <hip/hip_runtime.h>
#include <hip/hip_bf16.h>

// h = x(65536x512) @ W^T(512x256) + bias_lin ; GroupNorm(8 groups of 32)
// ; min over 256 channels -> m[b] ; out[c*B+b] = m[b] + bias[c]
//
// R5: non-persistent. Grid 2048 x 512 threads (8 waves), tile = 32 rows.
// Wave w owns GN group w (cols 32w..32w+31), computed in TWO 16-col passes so
// only 64 B-VGPRs are live at once (loaded fresh per pass -> compiler keeps
// them; no reload-in-K-loop pathology). Epilogue = in-wave 16-lane butterflies
// (R3-proven, ~0 conflicts). Broadcast store fused. 2 blocks/CU.
#define B_ROWS 65536
#define K_DIM  512
#define EPS    1e-5f
#define MTILE  32
#define XSTR   520    // shorts; 1040B row stride, 16B-aligned

using short8  = __attribute__((ext_vector_type(8))) short;
using floatx4 = __attribute__((ext_vector_type(4))) float;

__device__ __forceinline__ unsigned short f2bf(float f) {
    unsigned u = __builtin_bit_cast(unsigned, f);
    u += 0x7FFFu + ((u >> 16) & 1u);     // RNE
    return (unsigned short)(u >> 16);
}

// Pack W (256x512 fp32) into bf16 MFMA B-fragment order:
// P[((nt*16 + kk)*64 + lane)*8 + j] = bf16(W[nt*16 + (lane&15)][kk*32 + (lane>>4)*8 + j])
__global__ __launch_bounds__(64) void pack_w(const float* __restrict__ W,
                                             unsigned short* __restrict__ P) {
    int b    = blockIdx.x;           // 0..255
    int nt   = b >> 4, kk = b & 15;
    int lane = threadIdx.x;
    int l15  = lane & 15, quad = lane >> 4;
    const float* src = W + (size_t)(nt * 16 + l15) * K_DIM + kk * 32 + quad * 8;
    short8 v;
#pragma unroll
    for (int j = 0; j < 8; ++j) v[j] = (short)f2bf(src[j]);
    *(short8*)(P + ((size_t)(nt * 16 + kk) * 64 + lane) * 8) = v;
}

__global__ __launch_bounds__(512, 4) void fused(
    const float* __restrict__ X, const unsigned short* __restrict__ P,
    const float* __restrict__ bias_lin, const float* __restrict__ wgn,
    const float* __restrict__ bgn, const float* __restrict__ bias,
    float* __restrict__ out)
{
    __shared__ unsigned short Ash[MTILE * XSTR];   // 33280 B
    __shared__ float Msh[MTILE * 8];               // per-(row,group) mins
    __shared__ float m_sh[MTILE];

    const int tid  = threadIdx.x;
    const int wave = tid >> 6, lane = tid & 63;
    const int l15  = lane & 15, quad = lane >> 4;
    const int t    = blockIdx.x;
    const size_t row0 = (size_t)t * MTILE;

    // ---- pass-0 B fragments (cols 32w .. 32w+15): 16 x b128 from L2 ----
    short8 bfr[16];
    {
        const unsigned short* p0 = P + (((size_t)(2 * wave) * 16) * 64 + lane) * 8;
#pragma unroll
        for (int kk = 0; kk < 16; ++kk)
            bfr[kk] = *(const short8*)(p0 + (size_t)kk * 64 * 8);
    }

    // ---- stage x tile: 32 rows x 512 fp32 -> bf16 LDS ----
    {
        const int sr = tid >> 4, sc = tid & 15;     // row, 32-float chunk
        const float* xp = X + (row0 + sr) * K_DIM + sc * 32;
        float4 f[8];
#pragma unroll
        for (int p = 0; p < 8; ++p) f[p] = *(const float4*)(xp + p * 4);
#pragma unroll
        for (int pq = 0; pq < 4; ++pq) {
            short8 v;
            v[0] = (short)f2bf(f[2*pq].x);   v[1] = (short)f2bf(f[2*pq].y);
            v[2] = (short)f2bf(f[2*pq].z);   v[3] = (short)f2bf(f[2*pq].w);
            v[4] = (short)f2bf(f[2*pq+1].x); v[5] = (short)f2bf(f[2*pq+1].y);
            v[6] = (short)f2bf(f[2*pq+1].z); v[7] = (short)f2bf(f[2*pq+1].w);
            *(short8*)&Ash[sr * XSTR + sc * 32 + pq * 8] = v;
        }
    }
    __syncthreads();

    // ---- pass 0: cols 32w..32w+15 ----
    floatx4 accA0 = {0.f,0.f,0.f,0.f}, accA1 = {0.f,0.f,0.f,0.f};
#pragma unroll
    for (int kk = 0; kk < 16; ++kk) {
        short8 a0 = *(const short8*)&Ash[l15 * XSTR + kk * 32 + quad * 8];
        short8 a1 = *(const short8*)&Ash[(16 + l15) * XSTR + kk * 32 + quad * 8];
        accA0 = __builtin_amdgcn_mfma_f32_16x16x32_bf16(a0, bfr[kk], accA0, 0, 0, 0);
        accA1 = __builtin_amdgcn_mfma_f32_16x16x32_bf16(a1, bfr[kk], accA1, 0, 0, 0);
    }
    __builtin_amdgcn_sched_barrier(0);   // keep pass-1 B loads from hoisting above

    // ---- pass-1 B fragments (cols 32w+16 .. 32w+31) ----
    {
        const unsigned short* p1 = P + (((size_t)(2 * wave + 1) * 16) * 64 + lane) * 8;
#pragma unroll
        for (int kk = 0; kk < 16; ++kk)
            bfr[kk] = *(const short8*)(p1 + (size_t)kk * 64 * 8);
    }
    floatx4 accB0 = {0.f,0.f,0.f,0.f}, accB1 = {0.f,0.f,0.f,0.f};
#pragma unroll
    for (int kk = 0; kk < 16; ++kk) {
        short8 a0 = *(const short8*)&Ash[l15 * XSTR + kk * 32 + quad * 8];
        short8 a1 = *(const short8*)&Ash[(16 + l15) * XSTR + kk * 32 + quad * 8];
        accB0 = __builtin_amdgcn_mfma_f32_16x16x32_bf16(a0, bfr[kk], accB0, 0, 0, 0);
        accB1 = __builtin_amdgcn_mfma_f32_16x16x32_bf16(a1, bfr[kk], accB1, 0, 0, 0);
    }

    // ---- epilogue: group w stats via 16-lane butterflies (cols l15 & l15+16) ----
    const int c0 = wave * 32 + l15, c1 = c0 + 16;
    const float bl0 = bias_lin[c0], bl1 = bias_lin[c1];
    const float wg0 = wgn[c0], wg1 = wgn[c1];
    const float bg0 = bgn[c0], bg1 = bgn[c1];

#pragma unroll
    for (int rs = 0; rs < 2; ++rs) {
        floatx4 aA = rs ? accA1 : accA0;
        floatx4 aB = rs ? accB1 : accB0;
#pragma unroll
        for (int reg = 0; reg < 4; ++reg) {
            float va = aA[reg] + bl0;
            float vb = aB[reg] + bl1;
            float s = va + vb, ss = va * va + vb * vb;
#pragma unroll
            for (int m = 1; m < 16; m <<= 1) {
                s  += __shfl_xor(s, m);
                ss += __shfl_xor(ss, m);
            }
            float mean = s * (1.0f / 32.0f);
            float var  = ss * (1.0f / 32.0f) - mean * mean;
            float inv  = rsqrtf(var + EPS);
            float ga = (va - mean) * inv * wg0 + bg0;
            float gb = (vb - mean) * inv * wg1 + bg1;
            float mn = fminf(ga, gb);
#pragma unroll
            for (int m = 1; m < 16; m <<= 1) mn = fminf(mn, __shfl_xor(mn, m));
            if (l15 == 0) Msh[(rs * 16 + quad * 4 + reg) * 8 + wave] = mn;
        }
    }
    __syncthreads();
    if (tid < MTILE) {
        float m0 = Msh[tid * 8 + 0];
#pragma unroll
        for (int g = 1; g < 8; ++g) m0 = fminf(m0, Msh[tid * 8 + g]);
        m_sh[tid] = m0;
    }
    __syncthreads();

    // ---- broadcast store: out[c*B + row0 + j] = m[j] + bias[c], 4 c's/thread ----
    {
        float4 mv = *(const float4*)&m_sh[(tid & 7) * 4];
        const int cb = tid >> 3;                    // 0..63
#pragma unroll
        for (int j = 0; j < 4; ++j) {
            int c = cb + 64 * j;
            float bc = bias[c];
            float4 o;
            o.x = mv.x + bc; o.y = mv.y + bc; o.z = mv.z + bc; o.w = mv.w + bc;
            *(float4*)(out + (size_t)c * B_ROWS + row0 + (tid & 7) * 4) = o;
        }
    }
}

extern "C" void kernel_launch(void* const* d_in, const int* in_sizes, int n_in,
                              void* d_out, int out_size, void* d_ws, size_t ws_size,
                              hipStream_t stream) {
    const float* x    = (const float*)d_in[0];
    const float* w    = (const float*)d_in[1];
    const float* bl   = (const float*)d_in[2];
    const float* wg   = (const float*)d_in[3];
    const float* bg   = (const float*)d_in[4];
    const float* bias = (const float*)d_in[5];

    unsigned short* P = (unsigned short*)d_ws;     // 256 KB packed bf16 W
    float* out = (float*)d_out;

    hipLaunchKernelGGL(pack_w, dim3(256), dim3(64), 0, stream, w, P);
    hipLaunchKernelGGL(fused, dim3(B_ROWS / MTILE), dim3(512), 0, stream,
                       x, P, bl, wg, bg, bias, out);
}